// Round 3
// baseline (621.572 us; speedup 1.0000x reference)
//
#include <hip/hip_runtime.h>

typedef unsigned short ushort_t;
typedef short s8v __attribute__((ext_vector_type(8)));
typedef unsigned short ushort8 __attribute__((ext_vector_type(8)));
typedef float floatx4 __attribute__((ext_vector_type(4)));

#define MFMA16(a, b, c) __builtin_amdgcn_mfma_f32_16x16x32_bf16((a), (b), (c), 0, 0, 0)

static constexpr int B_SZ = 8;
static constexpr int L = 8192;
static constexpr int H = 1024;
static constexpr int M_TOT = B_SZ * L;        // 65536 rows
static constexpr int S_CH = 128;              // chunk length == gemm1 row-tile
static constexpr int NC = L / S_CH;           // 64 chunks per batch

// round-to-nearest-even fp32 -> bf16 bits (host-side build kernels)
__device__ inline ushort_t f2bf(float f) {
    union { float f; unsigned u; } v; v.f = f;
    unsigned r = v.u + 0x7fffu + ((v.u >> 16) & 1u);
    return (ushort_t)(r >> 16);
}

// packed f32x2 -> bf16x2 (RNE) in one instruction
__device__ inline unsigned cvtpk(float lo, float hi) {
    unsigned r;
    asm("v_cvt_pk_bf16_f32 %0, %1, %2" : "=v"(r) : "v"(lo), "v"(hi));
    return r;
}

typedef union { s8v v; unsigned u[4]; } u32x4;

// async global->LDS, 16B per lane; lds dest = wave-uniform base + lane*16
__device__ inline void gload_lds16(const void* g, void* l) {
    __builtin_amdgcn_global_load_lds(
        (const __attribute__((address_space(1))) void*)g,
        (__attribute__((address_space(3))) void*)l, 16, 0, 0);
}

// ---------------------------------------------------------------- params ----
// params[0..63]=dA_r [64..127]=dA_i [128..191]=s_r [192..255]=s_i
// dApow INTERLEAVED: dApow[k*128 + 2p] = Re(dA^k), [k*128+2p+1] = Im(dA^k)
__global__ void params_kernel(const float* __restrict__ A_real,
                              const float* __restrict__ A_imag,
                              const float* __restrict__ inv_dt,
                              float* __restrict__ params,
                              float* __restrict__ dApow) {
    int p = threadIdx.x;  // 64 threads
    float x = inv_dt[p];
    float dt = (x > 20.f) ? x : log1pf(expf(x));
    float ar = A_real[p], ai = A_imag[p];
    float dr = 1.f - 0.5f * dt * ar;
    float di = -0.5f * dt * ai;
    float inv = 1.f / fmaf(dr, dr, di * di);
    float nr = 1.f + 0.5f * dt * ar, ni = 0.5f * dt * ai;
    float dAr = (nr * dr + ni * di) * inv;
    float dAi = (ni * dr - nr * di) * inv;
    params[p]       = dAr;
    params[64 + p]  = dAi;
    params[128 + p] = dt * dr * inv;    // Re(dt/den)
    params[192 + p] = -dt * di * inv;   // Im(dt/den)
    float pr = 1.f, pi = 0.f;
    dApow[2 * p] = 1.f; dApow[2 * p + 1] = 0.f;
    for (int k = 1; k <= S_CH; k++) {
        float npr = pr * dAr - pi * dAi;
        float npi = pr * dAi + pi * dAr;
        pr = npr; pi = npi;
        dApow[k * 128 + 2 * p]     = pr;
        dApow[k * 128 + 2 * p + 1] = pi;
    }
}

// -------------------------------------------------- build bf16 weights ----
// SWIZZLED granule layout for both W1T and CeffT (16B granules):
//   byte(granule) = tile*8192 + g*16,  g = n*4 + (q ^ ((n>>1)&3))
// W1T logical rows (n): 2p = Re(s_p*B[p][k]), 2p+1 = Im(s_p*B[p][k]);
//   tiles ti = k/32 (k in 0..1023), 32 tiles.
// CeffT logical: n = h%128 within ct = h/128; Ceff[h][2p]=2Cr, [2p+1]=-2Ci;
//   tiles (ct*4 + k/32), k in 0..127.
__global__ void build_w(const float* __restrict__ Br, const float* __restrict__ Bi,
                        const float* __restrict__ Cr, const float* __restrict__ Ci,
                        const float* __restrict__ params,
                        ushort_t* __restrict__ W1T, ushort_t* __restrict__ CeffT) {
    int t = blockIdx.x * 256 + threadIdx.x;   // 32768 granule-threads
    if (t < 16384) {
        int ti = t >> 9, g = t & 511;
        int n = g >> 2;
        int qq = (g & 3) ^ ((n >> 1) & 3);
        int kb = ti * 32 + qq * 8;
        int p = n >> 1;
        float sr = params[128 + p], si = params[192 + p];
        ushort8 o;
        #pragma unroll
        for (int e = 0; e < 8; e++) {
            int k = kb + e;
            float br = Br[p * 1024 + k], bi = Bi[p * 1024 + k];
            float v = (n & 1) ? (sr * bi + si * br) : (sr * br - si * bi);
            o[e] = f2bf(v);
        }
        *(ushort8*)&W1T[t * 8] = o;
    } else {
        int t2 = t - 16384;
        int ct_ti = t2 >> 9, g = t2 & 511;
        int ct = ct_ti >> 2, ti = ct_ti & 3;
        int n = g >> 2;
        int h = ct * 128 + n;
        int qq = (g & 3) ^ ((n >> 1) & 3);
        int kb = ti * 32 + qq * 8;
        ushort8 o;
        #pragma unroll
        for (int e = 0; e < 8; e++) {
            int k = kb + e;
            int p = k >> 1;
            float v = (k & 1) ? -2.f * Ci[h * 64 + p] : 2.f * Cr[h * 64 + p];
            o[e] = f2bf(v);
        }
        *(ushort8*)&CeffT[t2 * 8] = o;
    }
}

// -------------------------------------------- GEMM 1 + fused local scan ----
// A (u) direct global->reg with cvt_pk conversion; B (W1T) staged to LDS in
// 4 x 64KB phases via global_load_lds, swizzled conflict-free. Scan epilogue
// reuses the LDS (bus aliases B region).
__global__ __launch_bounds__(256) void gemm1s(const float* __restrict__ u,
                                              const ushort_t* __restrict__ W1T,
                                              const float* __restrict__ params,
                                              const float* __restrict__ dApow,
                                              float* __restrict__ hloc,
                                              float* __restrict__ endbuf) {
    __shared__ ushort_t Blds[32768];            // 64 KB
    float* bus = (float*)Blds;                  // aliased for scan epilogue
    int tid = threadIdx.x;
    int wave = tid >> 6, lane = tid & 63;
    int q = lane >> 4, mn = lane & 15;
    int swz = q ^ ((mn >> 1) & 3);
    size_t row0 = (size_t)blockIdx.x * 128;

    const float* uA0 = u + (row0 + wave * 32 + mn) * 1024 + q * 8;
    const float* uA1 = uA0 + 16 * 1024;

    floatx4 acc[2][8] = {};

    for (int ph = 0; ph < 4; ph++) {
        if (ph) __syncthreads();                // done reading previous phase
        {   // stage 64KB of swizzled W1T (tiles ph*8 .. ph*8+7), linear copy
            const ushort_t* gsrc = W1T + (size_t)ph * 32768 + wave * 512 + lane * 8;
            ushort_t* ldst = Blds + wave * 512;
            #pragma unroll
            for (int it = 0; it < 16; it++)
                gload_lds16(gsrc + it * 2048, ldst + it * 2048);
        }
        __syncthreads();                        // drain: B phase ready
        const float* ua0 = uA0 + ph * 256;
        const float* ua1 = uA1 + ph * 256;
        #pragma unroll
        for (int kt = 0; kt < 8; kt++) {
            float4 f00 = *(const float4*)(ua0 + kt * 32);
            float4 f01 = *(const float4*)(ua0 + kt * 32 + 4);
            float4 f10 = *(const float4*)(ua1 + kt * 32);
            float4 f11 = *(const float4*)(ua1 + kt * 32 + 4);
            u32x4 pa0, pa1;
            pa0.u[0] = cvtpk(f00.x, f00.y); pa0.u[1] = cvtpk(f00.z, f00.w);
            pa0.u[2] = cvtpk(f01.x, f01.y); pa0.u[3] = cvtpk(f01.z, f01.w);
            pa1.u[0] = cvtpk(f10.x, f10.y); pa1.u[1] = cvtpk(f10.z, f10.w);
            pa1.u[2] = cvtpk(f11.x, f11.y); pa1.u[3] = cvtpk(f11.z, f11.w);
            int bofs = kt * 4096 + swz * 8;
            #pragma unroll
            for (int j = 0; j < 8; j++) {
                s8v bf = *(const s8v*)&Blds[bofs + (j * 16 + mn) * 32];
                acc[0][j] = MFMA16(pa0.v, bf, acc[0][j]);
                acc[1][j] = MFMA16(pa1.v, bf, acc[1][j]);
            }
        }
    }
    __syncthreads();   // B dead; safe to overwrite LDS with Bu tile
    #pragma unroll
    for (int i = 0; i < 2; i++)
        #pragma unroll
        for (int j = 0; j < 8; j++)
            #pragma unroll
            for (int reg = 0; reg < 4; reg++) {
                int row = wave * 32 + i * 16 + q * 4 + reg;
                bus[row * 128 + j * 16 + mn] = acc[i][j][reg];
            }
    __syncthreads();

    // --- wave-local scan over this wave's 32 rows (zero initial state) ---
    float dAr = params[lane], dAi = params[64 + lane];
    float hr = 0.f, hi = 0.f;
    int base = wave * 32 * 128 + 2 * lane;
    #pragma unroll 8
    for (int t = 0; t < 32; t++) {
        float2 v = *(float2*)&bus[base + t * 128];
        float nhr = fmaf(dAr, hr, fmaf(-dAi, hi, v.x));
        float nhi = fmaf(dAr, hi, fmaf(dAi, hr, v.y));
        hr = nhr; hi = nhi;
        *(float2*)&bus[base + t * 128] = make_float2(hr, hi);
    }
    __syncthreads();

    // --- cross-wave carry: c_w = sum_{w'<w} dA^(32*(w-1-w')) * e_{w'} ---
    float a32r = dApow[32 * 128 + 2 * lane], a32i = dApow[32 * 128 + 2 * lane + 1];
    float cr = 0.f, ci = 0.f;
    for (int w2 = 0; w2 < wave; w2++) {
        float2 e = *(float2*)&bus[(w2 * 32 + 31) * 128 + 2 * lane];
        float tr = fmaf(a32r, cr, fmaf(-a32i, ci, e.x));
        float ti = fmaf(a32r, ci, fmaf(a32i, cr, e.y));
        cr = tr; ci = ti;
    }

    // --- correction + coalesced global write: h[l] = h_w[t] + dA^(t+1)*c_w ---
    float* gbase = hloc + (row0 + wave * 32) * 128 + 2 * lane;
    float lr = 0.f, li = 0.f;
    #pragma unroll 8
    for (int t = 0; t < 32; t++) {
        float2 v = *(float2*)&bus[base + t * 128];
        float pr = dApow[(t + 1) * 128 + 2 * lane];
        float pi = dApow[(t + 1) * 128 + 2 * lane + 1];
        float orr = v.x + pr * cr - pi * ci;
        float oi  = v.y + pr * ci + pi * cr;
        *(float2*)(gbase + (size_t)t * 128) = make_float2(orr, oi);
        lr = orr; li = oi;
    }
    if (wave == 3) {   // chunk end state (corrected h at local row 127)
        float* e = endbuf + (size_t)blockIdx.x * 128 + 2 * lane;
        e[0] = lr; e[1] = li;
    }
}

// --------------------------------------------------------- carry scan ----
// carry[c] = state entering chunk c; carry[0] = h0 (folds initial state).
__global__ void scan_carry(const float* __restrict__ endbuf,
                           const float* __restrict__ dApow,
                           const float* __restrict__ h0r,
                           const float* __restrict__ h0i,
                           float* __restrict__ carry) {
    int t = blockIdx.x * 64 + threadIdx.x;  // 512 = 8*64
    int b = t >> 6, p = t & 63;
    float aSr = dApow[S_CH * 128 + 2 * p], aSi = dApow[S_CH * 128 + 2 * p + 1];
    float cr = h0r[b * 64 + p], ci = h0i[b * 64 + p];
    for (int c = 0; c < NC; c++) {
        float* dst = carry + ((size_t)b * NC + c) * 128 + 2 * p;
        dst[0] = cr; dst[1] = ci;
        const float* e = endbuf + ((size_t)b * NC + c) * 128 + 2 * p;
        float er = e[0], ei = e[1];
        float nr = fmaf(aSr, cr, fmaf(-aSi, ci, er));
        float ni = fmaf(aSr, ci, fmaf(aSi, cr, ei));
        cr = nr; ci = ni;
    }
}

// ------------------------------------------------------------- GEMM 2 ----
// A (hfix) built in registers once: hloc + dA^(r+1)*carry -> bf16, held in
// 8 s8v across the whole ct loop. B (CeffT) staged swizzled via
// global_load_lds in 4 phases x 2 column-tiles. Emits h_last.
__global__ __launch_bounds__(256) void gemm2(const float* __restrict__ hloc,
                                             const ushort_t* __restrict__ CeffT,
                                             const float* __restrict__ u,
                                             const float* __restrict__ D,
                                             const float* __restrict__ dApow,
                                             const float* __restrict__ carry,
                                             float* __restrict__ y,
                                             float* __restrict__ out_hlast) {
    __shared__ ushort_t Blds[32768];   // 64 KB: 2 column-tiles per phase
    int tid = threadIdx.x;
    int wave = tid >> 6, lane = tid & 63;
    int q = lane >> 4, mn = lane & 15;
    int swz = q ^ ((mn >> 1) & 3);
    size_t row0 = (size_t)blockIdx.x * 128;
    int b = blockIdx.x >> 6;          // batch
    int c = blockIdx.x & 63;          // chunk (S_CH==128==block rows)

    // ---- A fragments with fixup, in registers ----
    u32x4 A[2][4];
    #pragma unroll
    for (int i = 0; i < 2; i++) {
        int r_i = wave * 32 + i * 16 + mn;
        int kp = r_i + 1;
        const float* hrow = hloc + (row0 + r_i) * 128;
        const float* prow = dApow + (size_t)kp * 128;
        const float* crow = carry + ((size_t)b * NC + c) * 128;
        bool last = (c == NC - 1) && (r_i == 127);
        #pragma unroll
        for (int kt = 0; kt < 4; kt++) {
            int kb = kt * 32 + q * 8;
            float4 h0 = *(const float4*)(hrow + kb);
            float4 h1 = *(const float4*)(hrow + kb + 4);
            float4 p0 = *(const float4*)(prow + kb);
            float4 p1 = *(const float4*)(prow + kb + 4);
            float4 c0 = *(const float4*)(crow + kb);
            float4 c1 = *(const float4*)(crow + kb + 4);
            float f0 = h0.x + p0.x * c0.x - p0.y * c0.y;
            float f1 = h0.y + p0.x * c0.y + p0.y * c0.x;
            float f2 = h0.z + p0.z * c0.z - p0.w * c0.w;
            float f3 = h0.w + p0.z * c0.w + p0.w * c0.z;
            float f4 = h1.x + p1.x * c1.x - p1.y * c1.y;
            float f5 = h1.y + p1.x * c1.y + p1.y * c1.x;
            float f6 = h1.z + p1.z * c1.z - p1.w * c1.w;
            float f7 = h1.w + p1.z * c1.w + p1.w * c1.z;
            A[i][kt].u[0] = cvtpk(f0, f1); A[i][kt].u[1] = cvtpk(f2, f3);
            A[i][kt].u[2] = cvtpk(f4, f5); A[i][kt].u[3] = cvtpk(f6, f7);
            if (last) {
                int pb = kt * 16 + q * 4;
                out_hlast[b * 64 + pb]           = f0; out_hlast[512 + b * 64 + pb]     = f1;
                out_hlast[b * 64 + pb + 1]       = f2; out_hlast[512 + b * 64 + pb + 1] = f3;
                out_hlast[b * 64 + pb + 2]       = f4; out_hlast[512 + b * 64 + pb + 2] = f5;
                out_hlast[b * 64 + pb + 3]       = f6; out_hlast[512 + b * 64 + pb + 3] = f7;
            }
        }
    }

    for (int ph = 0; ph < 4; ph++) {
        if (ph) __syncthreads();
        {   // stage 64KB of swizzled CeffT (cts 2ph, 2ph+1), linear copy
            const ushort_t* gsrc = CeffT + (size_t)ph * 32768 + wave * 512 + lane * 8;
            ushort_t* ldst = Blds + wave * 512;
            #pragma unroll
            for (int it = 0; it < 16; it++)
                gload_lds16(gsrc + it * 2048, ldst + it * 2048);
        }
        __syncthreads();
        #pragma unroll
        for (int sub = 0; sub < 2; sub++) {
            int ct = ph * 2 + sub;
            floatx4 acc[2][8] = {};
            #pragma unroll
            for (int kt = 0; kt < 4; kt++) {
                int bofs = (sub * 4 + kt) * 4096 + swz * 8;
                #pragma unroll
                for (int j = 0; j < 8; j++) {
                    s8v bf = *(const s8v*)&Blds[bofs + (j * 16 + mn) * 32];
                    acc[0][j] = MFMA16(A[0][kt].v, bf, acc[0][j]);
                    acc[1][j] = MFMA16(A[1][kt].v, bf, acc[1][j]);
                }
            }
            float dv[8];
            #pragma unroll
            for (int j = 0; j < 8; j++) dv[j] = D[ct * 128 + j * 16 + mn];
            #pragma unroll
            for (int i = 0; i < 2; i++)
                #pragma unroll
                for (int j = 0; j < 8; j++) {
                    int col = ct * 128 + j * 16 + mn;
                    #pragma unroll
                    for (int reg = 0; reg < 4; reg++) {
                        size_t row = row0 + wave * 32 + i * 16 + q * 4 + reg;
                        y[row * 1024 + col] = acc[i][j][reg] + dv[j] * u[row * 1024 + col];
                    }
                }
        }
    }
}

// -------------------------------------------------------------- launch ----
extern "C" void kernel_launch(void* const* d_in, const int* in_sizes, int n_in,
                              void* d_out, int out_size, void* d_ws, size_t ws_size,
                              hipStream_t stream) {
    const float* u      = (const float*)d_in[0];
    const float* h_r    = (const float*)d_in[1];
    const float* h_i    = (const float*)d_in[2];
    const float* A_real = (const float*)d_in[3];
    const float* A_imag = (const float*)d_in[4];
    const float* B_real = (const float*)d_in[5];
    const float* B_imag = (const float*)d_in[6];
    const float* C_real = (const float*)d_in[7];
    const float* C_imag = (const float*)d_in[8];
    const float* D      = (const float*)d_in[9];
    const float* inv_dt = (const float*)d_in[10];
    float* out = (float*)d_out;

    // workspace layout (floats from base; all 16B aligned)
    float* wsf       = (float*)d_ws;
    float* P_params  = wsf;                    // 256 used, reserve 1024
    float* P_dApow   = wsf + 1024;             // 129*128 = 16512, reserve 16640
    float* P_carry   = wsf + 1024 + 16640;     // 8*NC*128 = 65536
    float* P_end     = P_carry + 65536;        // 65536
    ushort_t* P_W1T  = (ushort_t*)(P_end + 65536);      // 128*1024 bf16 (swizzled)
    ushort_t* P_Ceff = P_W1T + 128 * 1024;              // 1024*128 bf16 (swizzled)
    float* P_Bu      = (float*)(P_Ceff + 1024 * 128);   // 65536*128 f32 (33.5MB)

    params_kernel<<<1, 64, 0, stream>>>(A_real, A_imag, inv_dt, P_params, P_dApow);
    build_w<<<128, 256, 0, stream>>>(B_real, B_imag, C_real, C_imag, P_params, P_W1T, P_Ceff);
    gemm1s<<<M_TOT / 128, 256, 0, stream>>>(u, P_W1T, P_params, P_dApow, P_Bu, P_end);
    scan_carry<<<8, 64, 0, stream>>>(P_end, P_dApow, h_r, h_i, P_carry);
    gemm2<<<M_TOT / 128, 256, 0, stream>>>(P_Bu, P_Ceff, u, D, P_dApow, P_carry,
                                           out, out + (size_t)M_TOT * H);
}